// Round 9
// baseline (256.723 us; speedup 1.0000x reference)
//
#include <hip/hip_runtime.h>

#define KK 8
#define DD 16
#define NN 32
#define TT 200
#define BB 2048

// per-k LDS slab strides, == 4 (mod 32) floats and 16-B aligned ->
// <=8 distinct per-lane addresses spread across banks (broadcast-friendly)
#define SC 516
#define SA 260
#define SE 36
#define SD 20

// register-operand dot16; fold order IDENTICAL to all prior rounds
__device__ __forceinline__ float dot16r(float4 c0, float4 c1, float4 c2,
                                        float4 c3, const float* __restrict__ z) {
  float a = c0.x * z[0], b = c0.y * z[1];
  a = fmaf(c0.z, z[2], a);  b = fmaf(c0.w, z[3], b);
  a = fmaf(c1.x, z[4], a);  b = fmaf(c1.y, z[5], b);
  a = fmaf(c1.z, z[6], a);  b = fmaf(c1.w, z[7], b);
  a = fmaf(c2.x, z[8], a);  b = fmaf(c2.y, z[9], b);
  a = fmaf(c2.z, z[10], a); b = fmaf(c2.w, z[11], b);
  a = fmaf(c3.x, z[12], a); b = fmaf(c3.y, z[13], b);
  a = fmaf(c3.z, z[14], a); b = fmaf(c3.w, z[15], b);
  return a + b;
}

__device__ __forceinline__ void load16(float* __restrict__ d,
                                       const float* __restrict__ s) {
  const float4* p = reinterpret_cast<const float4*>(s);
  float4 a0 = p[0], a1 = p[1], a2 = p[2], a3 = p[3];
  d[0] = a0.x;  d[1] = a0.y;  d[2] = a0.z;  d[3] = a0.w;
  d[4] = a1.x;  d[5] = a1.y;  d[6] = a1.z;  d[7] = a1.w;
  d[8] = a2.x;  d[9] = a2.y;  d[10] = a2.z; d[11] = a2.w;
  d[12] = a3.x; d[13] = a3.y; d[14] = a3.z; d[15] = a3.w;
}

// THEORY (R9): R5 is at ~100% of the LDS RETURN PATH: 3.4 ds_read_b128
// per item x 1KB-to-RF x ~8cyc = 27 CU-cyc/item == measured 28.4 (44.5us).
// Occupancy-invariance (16->32 waves, R3 vs R5) confirms a per-CU pipe.
// Fix: SAME-K PAIRING. Block-local counting sort of 400 items; thread j
// owns sorted slots (2j,2j+1) -- ~197/200 pairs share k (<=7 bucket
// boundaries) -> each table row is loaded into REGISTERS once and dotted
// with both items' z. Mixed pairs re-load predicated (execz-skipped in
// uniform waves). LDS instrs/item 3.4 -> ~1.95 (floor ~15.6 CU-cyc/item).
// R8 lessons applied: NO LDS item staging (its 64-way-conflict gathers);
// z/zp/obs come from global -- divergent but inside a 51KB L2-hot window,
// on the otherwise-idle VMEM pipe. NO k-loop duplication (pairing, not
// passes). Per-item fold order is R5's EXACTLY (row-by-row acc sequence
// = same associativity). Natural-order lp staging + proven reduction.
__global__ __launch_bounds__(256) void slds_lp_kernel(
    const int* __restrict__ dsts,      // [B,T]
    const float* __restrict__ zg,      // [B,T,D]
    const float* __restrict__ obsg,    // [B,T,N]
    const float* __restrict__ initlg,  // [K]
    const float* __restrict__ initloc, // [K,D]
    const float* __restrict__ initls,  // [K,D]
    const float* __restrict__ transg,  // [K,K]
    const float* __restrict__ Ag,      // [K,D,D]
    const float* __restrict__ dynoff,  // [K,D]
    const float* __restrict__ dynls,   // [K,D] (scale directly, NOT log)
    const float* __restrict__ Cg,      // [K,N,D]
    const float* __restrict__ emoff,   // [K,N]
    const float* __restrict__ emls,    // [K,N]
    float* __restrict__ out)           // [B]
{
  __shared__ __align__(16) float sC[KK * SC];
  __shared__ __align__(16) float sA[KK * SA];
  __shared__ __align__(16) float sEmOff[KK * SE];
  __shared__ __align__(16) float sEmInv[KK * SE];
  __shared__ __align__(16) float sDynOff[KK * SD];
  __shared__ __align__(16) float sDynInv[KK * SD];
  __shared__ float sTrans[KK * KK];
  __shared__ float sEmConst[KK];
  __shared__ float sDynConst[KK];
  __shared__ float sInitLp[KK];
  __shared__ float lpS[400];
  __shared__ int   sidx[400];
  __shared__ int   cnt[KK];

  const float HALF_LOG2PI = 0.91893853320467274178f;
  const int tid = threadIdx.x;
  const int base = blockIdx.x * 400;

  if (tid < KK) cnt[tid] = 0;
  __syncthreads();

  // ---- stage tables (R5's transforms) + histogram, one barrier region ----
  for (int i = tid; i < KK * NN * DD; i += 256) {   // 4096
    int k = i >> 9, r = i & 511;
    sC[k * SC + r] = Cg[i];
  }
  for (int i = tid; i < KK * DD * DD; i += 256) {   // 2048
    int k = i >> 8, r = i & 255;
    sA[k * SA + r] = Ag[i];
  }
  if (tid < KK * NN) {
    int k = tid >> 5, n = tid & 31;
    sEmOff[k * SE + n] = emoff[tid];
    sEmInv[k * SE + n] = expf(-emls[tid]);
  }
  if (tid < KK * DD) {
    int k = tid >> 4, d = tid & 15;
    sDynOff[k * SD + d] = dynoff[tid];
    sDynInv[k * SD + d] = 1.0f / dynls[tid];
  }
  if (tid < KK * KK) {
    int kr = tid >> 3;
    float mx = transg[kr * KK];
    for (int j = 1; j < KK; ++j) mx = fmaxf(mx, transg[kr * KK + j]);
    float ss = 0.f;
    for (int j = 0; j < KK; ++j) ss += expf(transg[kr * KK + j] - mx);
    sTrans[tid] = transg[tid] - (logf(ss) + mx);
  }
  if (tid < KK) {
    int k = tid;
    float se = 0.f;
    for (int n = 0; n < NN; ++n) se -= emls[k * NN + n];
    sEmConst[k] = se - NN * HALF_LOG2PI;
    float sd = 0.f;
    for (int d = 0; d < DD; ++d) sd -= logf(dynls[k * DD + d]);
    sDynConst[k] = sd - DD * HALF_LOG2PI;
    float mx = initlg[0];
    for (int j = 1; j < KK; ++j) mx = fmaxf(mx, initlg[j]);
    float ss = 0.f;
    for (int j = 0; j < KK; ++j) ss += expf(initlg[j] - mx);
    float si = 0.f;
    for (int d = 0; d < DD; ++d) si -= initls[k * DD + d];
    sInitLp[k] = initlg[k] - (logf(ss) + mx) + si - DD * HALF_LOG2PI;
  }
  const int k0 = dsts[base + tid];                 // coalesced
  atomicAdd(&cnt[k0], 1);
  int k1 = 0;
  if (tid < 144) { k1 = dsts[base + 256 + tid]; atomicAdd(&cnt[k1], 1); }
  __syncthreads();
  if (tid == 0) {                                  // exclusive prefix
    int run = 0;
    for (int k = 0; k < KK; ++k) { int v = cnt[k]; cnt[k] = run; run += v; }
  }
  __syncthreads();
  {
    int pos = atomicAdd(&cnt[k0], 1);
    sidx[pos] = (tid << 3) | k0;
    if (tid < 144) {
      int pos1 = atomicAdd(&cnt[k1], 1);
      sidx[pos1] = ((tid + 256) << 3) | k1;
    }
  }
  __syncthreads();

  // ---- compute: thread j < 200 owns sorted slots (2j, 2j+1) ----
  if (tid < 200) {
    const int pA = sidx[2 * tid], pB = sidx[2 * tid + 1];
    const int ofA = pA >> 3, ofB = pB >> 3;        // natural offsets 0..399
    const int kA = pA & 7, kB = pB & 7;
    const int iA = base + ofA, iB = base + ofB;
    const int tA = iA - (iA / TT) * TT;
    const int tB = iB - (iB / TT) * TT;
    const int jA = iA - (tA != 0 ? 1 : 0);         // safe prev addr
    const int jB = iB - (tB != 0 ? 1 : 0);
    const int spA = dsts[jA], spB = dsts[jB];
    const bool same = (kA == kB);

    float zA[16], zB[16], zpA[16], zpB[16];
    load16(zA, zg + (size_t)iA * DD);
    load16(zB, zg + (size_t)iB * DD);
    load16(zpA, zg + (size_t)jA * DD);             // t==0: loads zA, discarded
    load16(zpB, zg + (size_t)jB * DD);

    float lpA, lpB;

    // ---- dynamics, rows shared when same-k (zp dies after this) ----
    {
      const float* __restrict__ AbA = &sA[kA * SA];
      const float* __restrict__ AbB = &sA[kB * SA];
      const int dA4 = kA * (SD / 4), dB4 = kB * (SD / 4);
      float accA = 0.f, accB = 0.f;
#define DYNROW(g, r, comp)                                                    \
      { const float4* rp = reinterpret_cast<const float4*>(&AbA[((g)*4+(r))*DD]); \
        float4 c0 = rp[0], c1 = rp[1], c2 = rp[2], c3 = rp[3];                \
        float lA_ = dot16r(c0, c1, c2, c3, zpA) + offA.comp;                  \
        if (!same) {                                                          \
          const float4* rq = reinterpret_cast<const float4*>(&AbB[((g)*4+(r))*DD]); \
          c0 = rq[0]; c1 = rq[1]; c2 = rq[2]; c3 = rq[3]; }                   \
        float lB_ = dot16r(c0, c1, c2, c3, zpB) + offB.comp;                  \
        float dA_ = (zA[(g)*4+(r)] - lA_) * invA.comp;                        \
        float dB_ = (zB[(g)*4+(r)] - lB_) * invB.comp;                        \
        accA = fmaf(dA_, dA_, accA); accB = fmaf(dB_, dB_, accB); }
#define DYNG(g)                                                               \
      { float4 offA = reinterpret_cast<const float4*>(sDynOff)[dA4 + (g)];    \
        float4 invA = reinterpret_cast<const float4*>(sDynInv)[dA4 + (g)];    \
        float4 offB = reinterpret_cast<const float4*>(sDynOff)[dB4 + (g)];    \
        float4 invB = reinterpret_cast<const float4*>(sDynInv)[dB4 + (g)];    \
        DYNROW(g, 0, x) DYNROW(g, 1, y) DYNROW(g, 2, z) DYNROW(g, 3, w) }
      DYNG(0) DYNG(1) DYNG(2) DYNG(3)
#undef DYNG
#undef DYNROW
      lpA = -0.5f * accA + sDynConst[kA] + sTrans[spA * KK + kA];
      lpB = -0.5f * accB + sDynConst[kB] + sTrans[spB * KK + kB];
    }

    // ---- rare t==0 overwrite (R5's exact init path, <=2 lanes/block) ----
    if (tA == 0) {
      const float* __restrict__ ploc = initloc + kA * DD;
      const float* __restrict__ pls  = initls + kA * DD;
      float a2 = 0.f;
#pragma unroll
      for (int g = 0; g < 4; ++g) {
        const int i0 = g * 4;
        float4 loc = reinterpret_cast<const float4*>(ploc)[g];
        float4 ls  = reinterpret_cast<const float4*>(pls)[g];
        float d0 = (zA[i0 + 0] - loc.x) * expf(-ls.x);
        float d1 = (zA[i0 + 1] - loc.y) * expf(-ls.y);
        float d2 = (zA[i0 + 2] - loc.z) * expf(-ls.z);
        float d3 = (zA[i0 + 3] - loc.w) * expf(-ls.w);
        a2 = fmaf(d0, d0, a2); a2 = fmaf(d1, d1, a2);
        a2 = fmaf(d2, d2, a2); a2 = fmaf(d3, d3, a2);
      }
      lpA = -0.5f * a2 + sInitLp[kA];
    }
    if (tB == 0) {
      const float* __restrict__ ploc = initloc + kB * DD;
      const float* __restrict__ pls  = initls + kB * DD;
      float a2 = 0.f;
#pragma unroll
      for (int g = 0; g < 4; ++g) {
        const int i0 = g * 4;
        float4 loc = reinterpret_cast<const float4*>(ploc)[g];
        float4 ls  = reinterpret_cast<const float4*>(pls)[g];
        float d0 = (zB[i0 + 0] - loc.x) * expf(-ls.x);
        float d1 = (zB[i0 + 1] - loc.y) * expf(-ls.y);
        float d2 = (zB[i0 + 2] - loc.z) * expf(-ls.z);
        float d3 = (zB[i0 + 3] - loc.w) * expf(-ls.w);
        a2 = fmaf(d0, d0, a2); a2 = fmaf(d1, d1, a2);
        a2 = fmaf(d2, d2, a2); a2 = fmaf(d3, d3, a2);
      }
      lpB = -0.5f * a2 + sInitLp[kB];
    }

    // ---- emissions, rows shared when same-k; obs via global (VMEM pipe,
    //      divergent inside the block's 51KB L2-hot window) ----
    {
      const float* __restrict__ CbA = &sC[kA * SC];
      const float* __restrict__ CbB = &sC[kB * SC];
      const int eA4 = kA * (SE / 4), eB4 = kB * (SE / 4);
      const float4* oap = reinterpret_cast<const float4*>(obsg + (size_t)iA * NN);
      const float4* obp = reinterpret_cast<const float4*>(obsg + (size_t)iB * NN);
      float accA = 0.f, accB = 0.f;
#define EMROW(r, comp)                                                        \
      { const float4* rp = reinterpret_cast<const float4*>(&CbA[(n0 + (r)) * DD]); \
        float4 c0 = rp[0], c1 = rp[1], c2 = rp[2], c3 = rp[3];                \
        float lA_ = dot16r(c0, c1, c2, c3, zA) + offA.comp;                   \
        if (!same) {                                                          \
          const float4* rq = reinterpret_cast<const float4*>(&CbB[(n0 + (r)) * DD]); \
          c0 = rq[0]; c1 = rq[1]; c2 = rq[2]; c3 = rq[3]; }                   \
        float lB_ = dot16r(c0, c1, c2, c3, zB) + offB.comp;                   \
        float dA_ = (oA.comp - lA_) * invA.comp;                              \
        float dB_ = (oB.comp - lB_) * invB.comp;                              \
        accA = fmaf(dA_, dA_, accA); accB = fmaf(dB_, dB_, accB); }
#pragma unroll 1
      for (int g = 0; g < 8; ++g) {
        float4 oA = oap[g];
        float4 oB = obp[g];
        float4 offA = reinterpret_cast<const float4*>(sEmOff)[eA4 + g];
        float4 invA = reinterpret_cast<const float4*>(sEmInv)[eA4 + g];
        float4 offB = reinterpret_cast<const float4*>(sEmOff)[eB4 + g];
        float4 invB = reinterpret_cast<const float4*>(sEmInv)[eB4 + g];
        const int n0 = g * 4;
        EMROW(0, x) EMROW(1, y) EMROW(2, z) EMROW(3, w)
      }
#undef EMROW
      lpA += -0.5f * accA + sEmConst[kA];
      lpB += -0.5f * accB + sEmConst[kB];
    }

    lpS[ofA] = lpA;                                // restore natural order
    lpS[ofB] = lpB;
  }
  __syncthreads();

  // ---- proven natural-order segmented shuffle-sum (R3/R5/R7) ----
  const int lane = tid & 63;
  for (int ofs = tid; ofs < 400; ofs += 256) {
    const int item = base + ofs;
    const int b = item / TT;
    float v = lpS[ofs];
#pragma unroll
    for (int off = 1; off < 64; off <<= 1) {
      float ov = __shfl_up(v, off, 64);
      int obk = __shfl_up(b, off, 64);
      if (lane >= off && obk == b) v += ov;
    }
    int nb = __shfl_down(b, 1, 64);
    if (lane == 63 || ofs == 399 || nb != b) atomicAdd(&out[b], v);
  }
}

extern "C" void kernel_launch(void* const* d_in, const int* in_sizes, int n_in,
                              void* d_out, int out_size, void* d_ws, size_t ws_size,
                              hipStream_t stream) {
  const int*   dsts    = (const int*)d_in[0];
  const float* zg      = (const float*)d_in[1];
  const float* obsg    = (const float*)d_in[2];
  const float* initlg  = (const float*)d_in[3];
  const float* initloc = (const float*)d_in[4];
  const float* initls  = (const float*)d_in[5];
  const float* transg  = (const float*)d_in[6];
  const float* Ag      = (const float*)d_in[7];
  const float* dynoff  = (const float*)d_in[8];
  const float* dynls   = (const float*)d_in[9];
  const float* Cg      = (const float*)d_in[10];
  const float* emoff   = (const float*)d_in[11];
  const float* emls    = (const float*)d_in[12];
  float* out = (float*)d_out;

  hipMemsetAsync(d_out, 0, BB * sizeof(float), stream);

  // 1024 blocks x 400 items (200 same-k pairs after block-local sort)
  // == exactly B*T; uniform 4 blocks/CU, single round
  slds_lp_kernel<<<1024, 256, 0, stream>>>(dsts, zg, obsg, initlg, initloc,
                                           initls, transg, Ag, dynoff, dynls,
                                           Cg, emoff, emls, out);
}

// Round 11
// 166.910 us; speedup vs baseline: 1.5381x; 1.5381x over previous
//
#include <hip/hip_runtime.h>

#define KK 8
#define DD 16
#define NN 32
#define TT 200
#define BB 2048
#define NPAD 408   // 400 + <=8 bucket-evening pads

// per-k LDS slab strides, == 4 (mod 32) floats and 16-B aligned ->
// <=8 distinct per-lane addresses spread across banks (broadcast-friendly)
#define SC 516
#define SA 260
#define SE 36
#define SD 20

// register-operand dot16; fold order IDENTICAL to all prior rounds
__device__ __forceinline__ float dot16r(float4 c0, float4 c1, float4 c2,
                                        float4 c3, const float* __restrict__ z) {
  float a = c0.x * z[0], b = c0.y * z[1];
  a = fmaf(c0.z, z[2], a);  b = fmaf(c0.w, z[3], b);
  a = fmaf(c1.x, z[4], a);  b = fmaf(c1.y, z[5], b);
  a = fmaf(c1.z, z[6], a);  b = fmaf(c1.w, z[7], b);
  a = fmaf(c2.x, z[8], a);  b = fmaf(c2.y, z[9], b);
  a = fmaf(c2.z, z[10], a); b = fmaf(c2.w, z[11], b);
  a = fmaf(c3.x, z[12], a); b = fmaf(c3.y, z[13], b);
  a = fmaf(c3.z, z[14], a); b = fmaf(c3.w, z[15], b);
  return a + b;
}

__device__ __forceinline__ void load16(float* __restrict__ d,
                                       const float* __restrict__ s) {
  const float4* p = reinterpret_cast<const float4*>(s);
  float4 a0 = p[0], a1 = p[1], a2 = p[2], a3 = p[3];
  d[0] = a0.x;  d[1] = a0.y;  d[2] = a0.z;  d[3] = a0.w;
  d[4] = a1.x;  d[5] = a1.y;  d[6] = a1.z;  d[7] = a1.w;
  d[8] = a2.x;  d[9] = a2.y;  d[10] = a2.z; d[11] = a2.w;
  d[12] = a3.x; d[13] = a3.y; d[14] = a3.z; d[15] = a3.w;
}

// THEORY (R11 == R10 resubmitted; R10 bench died to container infra, the
// kernel never ran -- audit found no OOB/barrier/LDS hazards):
// R5 sits at ~96% of the LDS return path (3.4 ds_read_b128/item x 8cyc =
// 27.2 CU-cyc/item vs 28.4 measured; occupancy-invariant 16->32 waves).
// SAME-K PAIRING halves table reads: each table row is loaded into
// registers once and dotted with BOTH items' state.
// R9's failure (VGPR 256 + 119MB spill) came from per-row `if(!same)`
// branches keeping two operand sets alive. Fix: EVERY pair is same-k BY
// CONSTRUCTION -- each bucket of the block-local counting sort is padded
// to even count with a duplicate-of-first-slot entry whose valid bit is
// cleared (<=8 pads / 400 items; pad results discarded). Compute is
// straight-line, single k per pair, no conditional reloads.
// Item data (z/zp/obs) from GLOBAL, gathered within the block's 51KB
// L1/L2-hot window (R8's LDS gathers = 64-way conflicts; R6's global-wide
// gathers = cache misses; this is neither). Per-item fold order is R5's
// EXACTLY. GATES: VGPR<=128, WRITE_SIZE ~KBs (no spill), else revert R5.
__global__ __launch_bounds__(256) void slds_lp_kernel(
    const int* __restrict__ dsts,      // [B,T]
    const float* __restrict__ zg,      // [B,T,D]
    const float* __restrict__ obsg,    // [B,T,N]
    const float* __restrict__ initlg,  // [K]
    const float* __restrict__ initloc, // [K,D]
    const float* __restrict__ initls,  // [K,D]
    const float* __restrict__ transg,  // [K,K]
    const float* __restrict__ Ag,      // [K,D,D]
    const float* __restrict__ dynoff,  // [K,D]
    const float* __restrict__ dynls,   // [K,D] (scale directly, NOT log)
    const float* __restrict__ Cg,      // [K,N,D]
    const float* __restrict__ emoff,   // [K,N]
    const float* __restrict__ emls,    // [K,N]
    float* __restrict__ out)           // [B]
{
  __shared__ __align__(16) float sC[KK * SC];
  __shared__ __align__(16) float sA[KK * SA];
  __shared__ __align__(16) float sEmOff[KK * SE];
  __shared__ __align__(16) float sEmInv[KK * SE];
  __shared__ __align__(16) float sDynOff[KK * SD];
  __shared__ __align__(16) float sDynInv[KK * SD];
  __shared__ float sTrans[KK * KK];
  __shared__ float sEmConst[KK];
  __shared__ float sDynConst[KK];
  __shared__ float sInitLp[KK];
  __shared__ float lpS[400];
  __shared__ int   sidx[NPAD];
  __shared__ int   cnt[KK], poff[KK], cur[KK];
  __shared__ int   nslots;

  const float HALF_LOG2PI = 0.91893853320467274178f;
  const int tid = threadIdx.x;
  const int base = blockIdx.x * 400;

  if (tid < KK) cnt[tid] = 0;
  __syncthreads();

  // ---- stage tables (R5's transforms) + histogram ----
  for (int i = tid; i < KK * NN * DD; i += 256) {   // 4096
    int k = i >> 9, r = i & 511;
    sC[k * SC + r] = Cg[i];
  }
  for (int i = tid; i < KK * DD * DD; i += 256) {   // 2048
    int k = i >> 8, r = i & 255;
    sA[k * SA + r] = Ag[i];
  }
  if (tid < KK * NN) {
    int k = tid >> 5, n = tid & 31;
    sEmOff[k * SE + n] = emoff[tid];
    sEmInv[k * SE + n] = expf(-emls[tid]);
  }
  if (tid < KK * DD) {
    int k = tid >> 4, d = tid & 15;
    sDynOff[k * SD + d] = dynoff[tid];
    sDynInv[k * SD + d] = 1.0f / dynls[tid];
  }
  if (tid < KK * KK) {
    int kr = tid >> 3;
    float mx = transg[kr * KK];
    for (int j = 1; j < KK; ++j) mx = fmaxf(mx, transg[kr * KK + j]);
    float ss = 0.f;
    for (int j = 0; j < KK; ++j) ss += expf(transg[kr * KK + j] - mx);
    sTrans[tid] = transg[tid] - (logf(ss) + mx);
  }
  if (tid < KK) {
    int k = tid;
    float se = 0.f;
    for (int n = 0; n < NN; ++n) se -= emls[k * NN + n];
    sEmConst[k] = se - NN * HALF_LOG2PI;
    float sd = 0.f;
    for (int d = 0; d < DD; ++d) sd -= logf(dynls[k * DD + d]);
    sDynConst[k] = sd - DD * HALF_LOG2PI;
    float mx = initlg[0];
    for (int j = 1; j < KK; ++j) mx = fmaxf(mx, initlg[j]);
    float ss = 0.f;
    for (int j = 0; j < KK; ++j) ss += expf(initlg[j] - mx);
    float si = 0.f;
    for (int d = 0; d < DD; ++d) si -= initls[k * DD + d];
    sInitLp[k] = initlg[k] - (logf(ss) + mx) + si - DD * HALF_LOG2PI;
  }
  const int k0 = dsts[base + tid];                 // coalesced
  atomicAdd(&cnt[k0], 1);
  int k1 = 0;
  if (tid < 144) { k1 = dsts[base + 256 + tid]; atomicAdd(&cnt[k1], 1); }
  __syncthreads();
  if (tid == 0) {                                  // even-padded offsets
    int run = 0;
    for (int k = 0; k < KK; ++k) {
      poff[k] = run;
      run += (cnt[k] + 1) & ~1;                    // round bucket up to even
    }
    nslots = run;                                  // <= 408, always even
  }
  __syncthreads();
  if (tid < KK) cur[tid] = poff[tid];
  __syncthreads();
  {                                                // scatter: (iofs<<4)|(k<<1)|1
    int pos = atomicAdd(&cur[k0], 1);
    sidx[pos] = (tid << 4) | (k0 << 1) | 1;
    if (tid < 144) {
      int pos1 = atomicAdd(&cur[k1], 1);
      sidx[pos1] = ((tid + 256) << 4) | (k1 << 1) | 1;
    }
  }
  __syncthreads();
  if (tid < KK && (cnt[tid] & 1))                  // even the odd buckets:
    sidx[poff[tid] + cnt[tid]] = sidx[poff[tid]] & ~1;  // dup, valid=0
  __syncthreads();

  // ---- compute: thread j owns pair (2j, 2j+1); SAME k guaranteed ----
  if (2 * tid < nslots) {
    const int eA = sidx[2 * tid], eB = sidx[2 * tid + 1];
    const int ofA = eA >> 4, ofB = eB >> 4;
    const int k = (eA >> 1) & 7;                   // == (eB>>1)&7
    const bool vA = eA & 1, vB = eB & 1;
    const int iA = base + ofA, iB = base + ofB;
    const int tA = iA - (iA / TT) * TT;
    const int tB = iB - (iB / TT) * TT;
    const int jA = iA - (tA != 0 ? 1 : 0);
    const int jB = iB - (tB != 0 ? 1 : 0);
    const int spA = dsts[jA], spB = dsts[jB];

    float zA[16], zB[16], zpA[16], zpB[16];
    load16(zA, zg + (size_t)iA * DD);
    load16(zB, zg + (size_t)iB * DD);
    load16(zpA, zg + (size_t)jA * DD);             // t==0: dup of zA, discarded
    load16(zpB, zg + (size_t)jB * DD);

    float lpA, lpB;

    // ---- dynamics: each A-row read ONCE, dotted with both zp's ----
    {
      const float* __restrict__ Ab = &sA[k * SA];
      const int d4 = k * (SD / 4);
      float accA = 0.f, accB = 0.f;
#define DYNROW(g, r, comp)                                                    \
      { const float4* rp = reinterpret_cast<const float4*>(&Ab[((g)*4+(r))*DD]); \
        float4 c0 = rp[0], c1 = rp[1], c2 = rp[2], c3 = rp[3];                \
        float lA_ = dot16r(c0, c1, c2, c3, zpA) + off.comp;                   \
        float lB_ = dot16r(c0, c1, c2, c3, zpB) + off.comp;                   \
        float dA_ = (zA[(g)*4+(r)] - lA_) * inv.comp;                         \
        float dB_ = (zB[(g)*4+(r)] - lB_) * inv.comp;                         \
        accA = fmaf(dA_, dA_, accA); accB = fmaf(dB_, dB_, accB); }
#define DYNG(g)                                                               \
      { float4 off = reinterpret_cast<const float4*>(sDynOff)[d4 + (g)];      \
        float4 inv = reinterpret_cast<const float4*>(sDynInv)[d4 + (g)];      \
        DYNROW(g, 0, x) DYNROW(g, 1, y) DYNROW(g, 2, z) DYNROW(g, 3, w) }
      DYNG(0) DYNG(1) DYNG(2) DYNG(3)
#undef DYNG
#undef DYNROW
      lpA = -0.5f * accA + sDynConst[k] + sTrans[spA * KK + k];
      lpB = -0.5f * accB + sDynConst[k] + sTrans[spB * KK + k];
    }

    // ---- rare t==0 overwrite (R5's exact init path, <=2 lanes/block) ----
    if (tA == 0) {
      const float* __restrict__ ploc = initloc + k * DD;
      const float* __restrict__ pls  = initls + k * DD;
      float a2 = 0.f;
#pragma unroll
      for (int g = 0; g < 4; ++g) {
        const int i0 = g * 4;
        float4 loc = reinterpret_cast<const float4*>(ploc)[g];
        float4 ls  = reinterpret_cast<const float4*>(pls)[g];
        float d0 = (zA[i0 + 0] - loc.x) * expf(-ls.x);
        float d1 = (zA[i0 + 1] - loc.y) * expf(-ls.y);
        float d2 = (zA[i0 + 2] - loc.z) * expf(-ls.z);
        float d3 = (zA[i0 + 3] - loc.w) * expf(-ls.w);
        a2 = fmaf(d0, d0, a2); a2 = fmaf(d1, d1, a2);
        a2 = fmaf(d2, d2, a2); a2 = fmaf(d3, d3, a2);
      }
      lpA = -0.5f * a2 + sInitLp[k];
    }
    if (tB == 0) {
      const float* __restrict__ ploc = initloc + k * DD;
      const float* __restrict__ pls  = initls + k * DD;
      float a2 = 0.f;
#pragma unroll
      for (int g = 0; g < 4; ++g) {
        const int i0 = g * 4;
        float4 loc = reinterpret_cast<const float4*>(ploc)[g];
        float4 ls  = reinterpret_cast<const float4*>(pls)[g];
        float d0 = (zB[i0 + 0] - loc.x) * expf(-ls.x);
        float d1 = (zB[i0 + 1] - loc.y) * expf(-ls.y);
        float d2 = (zB[i0 + 2] - loc.z) * expf(-ls.z);
        float d3 = (zB[i0 + 3] - loc.w) * expf(-ls.w);
        a2 = fmaf(d0, d0, a2); a2 = fmaf(d1, d1, a2);
        a2 = fmaf(d2, d2, a2); a2 = fmaf(d3, d3, a2);
      }
      lpB = -0.5f * a2 + sInitLp[k];
    }

    // ---- emissions: each C-row read ONCE, dotted with both z's; obs via
    //      global float4 gathers inside the block's 51KB L1/L2-hot window ----
    {
      const float* __restrict__ Cb = &sC[k * SC];
      const int e4 = k * (SE / 4);
      const float4* oap = reinterpret_cast<const float4*>(obsg + (size_t)iA * NN);
      const float4* obp = reinterpret_cast<const float4*>(obsg + (size_t)iB * NN);
      float accA = 0.f, accB = 0.f;
#define EMROW(r, comp)                                                        \
      { const float4* rp = reinterpret_cast<const float4*>(&Cb[(n0 + (r)) * DD]); \
        float4 c0 = rp[0], c1 = rp[1], c2 = rp[2], c3 = rp[3];                \
        float lA_ = dot16r(c0, c1, c2, c3, zA) + off.comp;                    \
        float lB_ = dot16r(c0, c1, c2, c3, zB) + off.comp;                    \
        float dA_ = (oA.comp - lA_) * inv.comp;                               \
        float dB_ = (oB.comp - lB_) * inv.comp;                               \
        accA = fmaf(dA_, dA_, accA); accB = fmaf(dB_, dB_, accB); }
#pragma unroll 1
      for (int g = 0; g < 8; ++g) {
        float4 oA = oap[g];
        float4 oB = obp[g];
        float4 off = reinterpret_cast<const float4*>(sEmOff)[e4 + g];
        float4 inv = reinterpret_cast<const float4*>(sEmInv)[e4 + g];
        const int n0 = g * 4;
        EMROW(0, x) EMROW(1, y) EMROW(2, z) EMROW(3, w)
      }
#undef EMROW
      lpA += -0.5f * accA + sEmConst[k];
      lpB += -0.5f * accB + sEmConst[k];
    }

    if (vA) lpS[ofA] = lpA;                        // restore natural order
    if (vB) lpS[ofB] = lpB;                        // pads discarded
  }
  __syncthreads();

  // ---- proven natural-order segmented shuffle-sum (R3/R5/R7) ----
  const int lane = tid & 63;
  for (int ofs = tid; ofs < 400; ofs += 256) {
    const int item = base + ofs;
    const int b = item / TT;
    float v = lpS[ofs];
#pragma unroll
    for (int off = 1; off < 64; off <<= 1) {
      float ov = __shfl_up(v, off, 64);
      int obk = __shfl_up(b, off, 64);
      if (lane >= off && obk == b) v += ov;
    }
    int nb = __shfl_down(b, 1, 64);
    if (lane == 63 || ofs == 399 || nb != b) atomicAdd(&out[b], v);
  }
}

extern "C" void kernel_launch(void* const* d_in, const int* in_sizes, int n_in,
                              void* d_out, int out_size, void* d_ws, size_t ws_size,
                              hipStream_t stream) {
  const int*   dsts    = (const int*)d_in[0];
  const float* zg      = (const float*)d_in[1];
  const float* obsg    = (const float*)d_in[2];
  const float* initlg  = (const float*)d_in[3];
  const float* initloc = (const float*)d_in[4];
  const float* initls  = (const float*)d_in[5];
  const float* transg  = (const float*)d_in[6];
  const float* Ag      = (const float*)d_in[7];
  const float* dynoff  = (const float*)d_in[8];
  const float* dynls   = (const float*)d_in[9];
  const float* Cg      = (const float*)d_in[10];
  const float* emoff   = (const float*)d_in[11];
  const float* emls    = (const float*)d_in[12];
  float* out = (float*)d_out;

  hipMemsetAsync(d_out, 0, BB * sizeof(float), stream);

  // 1024 blocks x 400 items (<=204 same-k pairs after padded block sort)
  // == exactly B*T; ~32KB LDS -> 4 blocks/CU, single round
  slds_lp_kernel<<<1024, 256, 0, stream>>>(dsts, zg, obsg, initlg, initloc,
                                           initls, transg, Ag, dynoff, dynls,
                                           Cg, emoff, emls, out);
}

// Round 12
// 138.931 us; speedup vs baseline: 1.8478x; 1.2014x over previous
//
#include <hip/hip_runtime.h>

#define KK 8
#define DD 16
#define NN 32
#define TT 200
#define BB 2048

// per-k LDS slab strides, == 4 (mod 32) floats AND multiples of 4 (16-B
// alignment for float4) so the <=8 distinct per-lane k values spread
// across banks -> conflict-free (broadcast) ds_read_b128
#define SC 516   // C slab stride (512 used)
#define SA 260   // A slab stride (256 used)
#define SE 36    // emission table stride (32 used)
#define SD 20    // dyn table stride (16 used)

__device__ __forceinline__ float dot16(const float* __restrict__ row,
                                       const float* __restrict__ z) {
  const float4* r4 = reinterpret_cast<const float4*>(row);
  float4 c0 = r4[0], c1 = r4[1], c2 = r4[2], c3 = r4[3];
  float a = c0.x * z[0], b = c0.y * z[1];
  a = fmaf(c0.z, z[2], a);  b = fmaf(c0.w, z[3], b);
  a = fmaf(c1.x, z[4], a);  b = fmaf(c1.y, z[5], b);
  a = fmaf(c1.z, z[6], a);  b = fmaf(c1.w, z[7], b);
  a = fmaf(c2.x, z[8], a);  b = fmaf(c2.y, z[9], b);
  a = fmaf(c2.z, z[10], a); b = fmaf(c2.w, z[11], b);
  a = fmaf(c3.x, z[12], a); b = fmaf(c3.y, z[13], b);
  a = fmaf(c3.z, z[14], a); b = fmaf(c3.w, z[15], b);
  return a + b;
}

// const-indexed register fill (keeps the array SROA-able into VGPRs)
__device__ __forceinline__ void load16(float* __restrict__ d,
                                       const float* __restrict__ s) {
  const float4* p = reinterpret_cast<const float4*>(s);
  float4 a0 = p[0], a1 = p[1], a2 = p[2], a3 = p[3];
  d[0] = a0.x;  d[1] = a0.y;  d[2] = a0.z;  d[3] = a0.w;
  d[4] = a1.x;  d[5] = a1.y;  d[6] = a1.z;  d[7] = a1.w;
  d[8] = a2.x;  d[9] = a2.y;  d[10] = a2.z; d[11] = a2.w;
  d[12] = a3.x; d[13] = a3.y; d[14] = a3.z; d[15] = a3.w;
}

// FINAL (R12 = R5 revert, per the pre-registered rule after R11's VGPR
// gate failed at 196). Session evidence for the ~42-45us plateau:
//  - R0/R2/R3/R5 (four variants): 42-45us, INVARIANT under 16->32
//    resident waves/CU and VGPR 44..68 -> saturated per-CU shared
//    resource (the LDS table-broadcast stream + its waitcnt serialization),
//    not latency, not occupancy.
//  - Table traffic to per-lane VMEM: R4 81us, R7 65us (gather chains).
//  - Global sort for scalar tables: R6 88us (kills item coalescing).
//  - LDS item staging: R8 125us (64-way gather conflicts).
//  - Same-k pairing (halves table reads): R9 spill 154us; R11 VGPR
//    196 -> 8 waves/CU, 65us. Register-infeasible at required occupancy.
// VGPR 44, LDS 29184 (4x512-thread blocks/CU = 2048-thread cap, 32
// waves/CU). A in LDS (global-A fatal: R4); init path global (1/200).
__global__ __launch_bounds__(512) void slds_lp_kernel(
    const int* __restrict__ dsts,      // [B,T]
    const float* __restrict__ zg,      // [B,T,D]
    const float* __restrict__ obsg,    // [B,T,N]
    const float* __restrict__ initlg,  // [K]
    const float* __restrict__ initloc, // [K,D]
    const float* __restrict__ initls,  // [K,D]
    const float* __restrict__ transg,  // [K,K]
    const float* __restrict__ Ag,      // [K,D,D]
    const float* __restrict__ dynoff,  // [K,D]
    const float* __restrict__ dynls,   // [K,D] (scale directly, NOT log)
    const float* __restrict__ Cg,      // [K,N,D]
    const float* __restrict__ emoff,   // [K,N]
    const float* __restrict__ emls,    // [K,N]
    float* __restrict__ out)           // [B]
{
  __shared__ __align__(16) float sC[KK * SC];
  __shared__ __align__(16) float sA[KK * SA];
  __shared__ __align__(16) float sEmOff[KK * SE];
  __shared__ __align__(16) float sEmInv[KK * SE];
  __shared__ __align__(16) float sDynOff[KK * SD];
  __shared__ __align__(16) float sDynInv[KK * SD];
  __shared__ float sTrans[KK * KK];
  __shared__ float sEmConst[KK];
  __shared__ float sDynConst[KK];
  __shared__ float sInitLp[KK];

  const float HALF_LOG2PI = 0.91893853320467274178f;
  const int tid = threadIdx.x;

  // ---- stage params into LDS (transforms applied once per block) ----
  for (int i = tid; i < KK * NN * DD; i += 512) {   // 4096
    int k = i >> 9, r = i & 511;
    sC[k * SC + r] = Cg[i];
  }
  for (int i = tid; i < KK * DD * DD; i += 512) {   // 2048
    int k = i >> 8, r = i & 255;
    sA[k * SA + r] = Ag[i];
  }
  if (tid < KK * NN) {                              // 256
    int k = tid >> 5, n = tid & 31;
    sEmOff[k * SE + n] = emoff[tid];
    sEmInv[k * SE + n] = expf(-emls[tid]);
  }
  if (tid < KK * DD) {                              // 128
    int k = tid >> 4, d = tid & 15;
    sDynOff[k * SD + d] = dynoff[tid];
    sDynInv[k * SD + d] = 1.0f / dynls[tid];
  }
  if (tid < KK * KK) {                              // 64: transition log-softmax
    int kr = tid >> 3;
    float mx = transg[kr * KK];
    for (int j = 1; j < KK; ++j) mx = fmaxf(mx, transg[kr * KK + j]);
    float ss = 0.f;
    for (int j = 0; j < KK; ++j) ss += expf(transg[kr * KK + j] - mx);
    sTrans[tid] = transg[tid] - (logf(ss) + mx);
  }
  if (tid < KK) {                                   // per-k constants
    int k = tid;
    float se = 0.f;
    for (int n = 0; n < NN; ++n) se -= emls[k * NN + n];
    sEmConst[k] = se - NN * HALF_LOG2PI;
    float sd = 0.f;
    for (int d = 0; d < DD; ++d) sd -= logf(dynls[k * DD + d]);
    sDynConst[k] = sd - DD * HALF_LOG2PI;
    float mx = initlg[0];
    for (int j = 1; j < KK; ++j) mx = fmaxf(mx, initlg[j]);
    float ss = 0.f;
    for (int j = 0; j < KK; ++j) ss += expf(initlg[j] - mx);
    float si = 0.f;
    for (int d = 0; d < DD; ++d) si -= initls[k * DD + d];
    sInitLp[k] = initlg[k] - (logf(ss) + mx) + si - DD * HALF_LOG2PI;
  }
  __syncthreads();

  // ---- block bk owns items [bk*400, bk*400+400) == exactly 2 batch
  //      elements; single pass, one item per thread, tid 400..511 idle ----
  if (tid < 400) {
    const int item = blockIdx.x * 400 + tid;
    const int b = item / TT;
    const int t = item - b * TT;

    float z[16];
    load16(z, zg + (size_t)item * DD);
    const int s = dsts[item];
    float lp;

    // ---- dynamics / init FIRST (zp dies before the emission loop) ----
    if (t != 0) {
      const int sp = dsts[item - 1];
      float zp[16];
      load16(zp, zg + (size_t)(item - 1) * DD);
      const float* __restrict__ Ab = &sA[s * SA];   // LDS, broadcast reads
      const int db4 = s * (SD / 4);
      float a2acc = 0.f;
      // FULL unroll: compile-time indices keep z/zp in VGPRs (rule #20)
#pragma unroll
      for (int g = 0; g < 4; ++g) {
        const int i0 = g * 4;
        float4 off = reinterpret_cast<const float4*>(sDynOff)[db4 + g];
        float4 inv = reinterpret_cast<const float4*>(sDynInv)[db4 + g];
        float l0 = dot16(&Ab[(i0 + 0) * DD], zp) + off.x;
        float l1 = dot16(&Ab[(i0 + 1) * DD], zp) + off.y;
        float l2 = dot16(&Ab[(i0 + 2) * DD], zp) + off.z;
        float l3 = dot16(&Ab[(i0 + 3) * DD], zp) + off.w;
        float d0 = (z[i0 + 0] - l0) * inv.x;
        float d1 = (z[i0 + 1] - l1) * inv.y;
        float d2 = (z[i0 + 2] - l2) * inv.z;
        float d3 = (z[i0 + 3] - l3) * inv.w;
        a2acc = fmaf(d0, d0, a2acc); a2acc = fmaf(d1, d1, a2acc);
        a2acc = fmaf(d2, d2, a2acc); a2acc = fmaf(d3, d3, a2acc);
      }
      lp = -0.5f * a2acc + sDynConst[s] + sTrans[sp * KK + s];
    } else {
      // rare (1/200): init tables straight from global + per-item expf
      // (same inputs, same formula -> bit-identical to staged version)
      const float* __restrict__ ploc = initloc + s * DD;
      const float* __restrict__ pls  = initls + s * DD;
      float a2acc = 0.f;
#pragma unroll
      for (int g = 0; g < 4; ++g) {
        const int i0 = g * 4;
        float4 loc = reinterpret_cast<const float4*>(ploc)[g];
        float4 ls  = reinterpret_cast<const float4*>(pls)[g];
        float d0 = (z[i0 + 0] - loc.x) * expf(-ls.x);
        float d1 = (z[i0 + 1] - loc.y) * expf(-ls.y);
        float d2 = (z[i0 + 2] - loc.z) * expf(-ls.z);
        float d3 = (z[i0 + 3] - loc.w) * expf(-ls.w);
        a2acc = fmaf(d0, d0, a2acc); a2acc = fmaf(d1, d1, a2acc);
        a2acc = fmaf(d2, d2, a2acc); a2acc = fmaf(d3, d3, a2acc);
      }
      lp = -0.5f * a2acc + sInitLp[s];
    }

    // ---- emissions (C in LDS -- the true reuse case) ----
    {
      const float4* o4 = reinterpret_cast<const float4*>(obsg + (size_t)item * NN);
      const int cb = s * SC;
      const int eb4 = s * (SE / 4);
      float acc = 0.f;
#pragma unroll 1
      for (int g = 0; g < 8; ++g) {
        float4 o = o4[g];
        float4 off = reinterpret_cast<const float4*>(sEmOff)[eb4 + g];
        float4 inv = reinterpret_cast<const float4*>(sEmInv)[eb4 + g];
        int n0 = g * 4;
        float l0 = dot16(&sC[cb + (n0 + 0) * DD], z) + off.x;
        float l1 = dot16(&sC[cb + (n0 + 1) * DD], z) + off.y;
        float l2 = dot16(&sC[cb + (n0 + 2) * DD], z) + off.z;
        float l3 = dot16(&sC[cb + (n0 + 3) * DD], z) + off.w;
        float d0 = (o.x - l0) * inv.x;
        float d1 = (o.y - l1) * inv.y;
        float d2 = (o.z - l2) * inv.z;
        float d3 = (o.w - l3) * inv.w;
        acc = fmaf(d0, d0, acc); acc = fmaf(d1, d1, acc);
        acc = fmaf(d2, d2, acc); acc = fmaf(d3, d3, acc);
      }
      lp += -0.5f * acc + sEmConst[s];
    }

    // ---- wave-level segmented sum keyed by b, then atomic.
    //      tid==399 guards the partial wave (lane 15 of wave 6 reads an
    //      inactive lane via shfl_down -> garbage nb; force its atomic). ----
    const int lane = tid & 63;
    float v = lp;
#pragma unroll
    for (int off = 1; off < 64; off <<= 1) {
      float ov = __shfl_up(v, off, 64);
      int obk = __shfl_up(b, off, 64);
      if (lane >= off && obk == b) v += ov;
    }
    int nb = __shfl_down(b, 1, 64);
    if (lane == 63 || tid == 399 || nb != b) atomicAdd(&out[b], v);
  }
}

extern "C" void kernel_launch(void* const* d_in, const int* in_sizes, int n_in,
                              void* d_out, int out_size, void* d_ws, size_t ws_size,
                              hipStream_t stream) {
  const int*   dsts    = (const int*)d_in[0];
  const float* zg      = (const float*)d_in[1];
  const float* obsg    = (const float*)d_in[2];
  const float* initlg  = (const float*)d_in[3];
  const float* initloc = (const float*)d_in[4];
  const float* initls  = (const float*)d_in[5];
  const float* transg  = (const float*)d_in[6];
  const float* Ag      = (const float*)d_in[7];
  const float* dynoff  = (const float*)d_in[8];
  const float* dynls   = (const float*)d_in[9];
  const float* Cg      = (const float*)d_in[10];
  const float* emoff   = (const float*)d_in[11];
  const float* emls    = (const float*)d_in[12];
  float* out = (float*)d_out;

  hipMemsetAsync(d_out, 0, BB * sizeof(float), stream);

  // 1024 blocks x 512 threads, 400 items each == exactly B*T.
  // 4 blocks/CU (2048-thread cap), 32 waves/CU resident at VGPR 44.
  slds_lp_kernel<<<1024, 512, 0, stream>>>(dsts, zg, obsg, initlg, initloc,
                                           initls, transg, Ag, dynoff, dynls,
                                           Cg, emoff, emls, out);
}